// Round 18
// baseline (763.588 us; speedup 1.0000x reference)
//
#include <hip/hip_runtime.h>
#include <hip/hip_fp16.h>

#define NN 20000
#define NE 300000
#define NT 500000
#define HD 128
#define NRR 6
#define NSNRD 42
#define NBB 8

using f16x8 = __attribute__((ext_vector_type(8))) _Float16;
using f32x4 = __attribute__((ext_vector_type(4))) float;

__device__ __forceinline__ float silu_f(float v){ return v / (1.f + __expf(-v)); }

__device__ __forceinline__ void pk_add(__half2* p, float lo, float hi){
  __half2 h = __floats2half2_rn(lo, hi);
  unsigned int b = *reinterpret_cast<unsigned int*>(&h);
  asm volatile("global_atomic_pk_add_f16 %0, %1, off" :: "v"(p), "v"(b) : "memory");
}

__device__ __forceinline__ void gload16(const void* g, char* lds_dst){
  __builtin_amdgcn_global_load_lds(
    (const __attribute__((address_space(1))) void*)g,
    (__attribute__((address_space(3))) void*)lds_dst, 16, 0, 0);
}

// ---- x fp32 -> fp16 (one pass) ----
__global__ void k_x16(const float* __restrict__ x, __half* __restrict__ xh){
  long i = ((long)blockIdx.x*256 + threadIdx.x)*8;
  if(i < (long)NE*HD){
    float4 a = *(const float4*)(x+i), b = *(const float4*)(x+i+4);
    __half h8[8];
    h8[0]=__float2half(a.x); h8[1]=__float2half(a.y);
    h8[2]=__float2half(a.z); h8[3]=__float2half(a.w);
    h8[4]=__float2half(b.x); h8[5]=__float2half(b.y);
    h8[6]=__float2half(b.z); h8[7]=__float2half(b.w);
    *(float4*)(xh+i) = *(float4*)h8;
  }
}

// ---- all weight prep in one launch (1088 blocks) ----
__global__ void k_prep(const float* __restrict__ Wb, __half* __restrict__ WB2,
                       const float* __restrict__ Wkj, const float* __restrict__ Wji,
                       const float* __restrict__ Wlin, __half* __restrict__ WkjT,
                       __half* __restrict__ WjiT, __half* __restrict__ WlinT,
                       const float* __restrict__ olW, __half* __restrict__ wo6){
  int bid = blockIdx.x, tid = threadIdx.x;
  if(bid < 512){
    int idx = bid*256 + tid;
    int l = idx & 127, i = (idx>>7) & 127, jb = idx>>14;
    WB2[jb*16384 + i*128 + l] = __float2half(Wb[i*1024 + jb*128 + l]);
  } else if(bid < 704){
    int idx = (bid-512)*256 + tid;
    int which = idx>>14, rem = idx & 16383;
    int i = rem>>7, k = rem & 127;
    const float* src = which==0 ? Wkj : (which==1 ? Wji : Wlin);
    __half* dst = which==0 ? WkjT : (which==1 ? WjiT : WlinT);
    dst[rem] = __float2half(src[k*HD + i]);
  } else {
    int idx = (bid-704)*256 + tid;
    int lw = idx>>14, rem = idx & 16383;
    int i = rem>>7, k = rem & 127;
    wo6[lw*16384 + rem] = __float2half(olW[lw*16384 + k*HD + i]);
  }
}

// ================= k_edge_pre (512 thr; rbf projections via MFMA K=32) ======
// A-frags + xval direct from global xh (no A tile). LDS: B 32K + rbfp/wrbfT/ls0T
// 10K each (rows padded to 40 fp16) + nids -> 63.5KB => 2 blocks/CU.
#define EROWS 128
#define PRE_B 0
#define PRE_RBF 32768
#define PRE_WR 43008
#define PRE_LS 53248
#define PRE_NID 63488
#define SH_PRE 64000
__global__ __launch_bounds__(512,4)
void k_edge_pre(const __half* __restrict__ xh, const float* __restrict__ rbf,
                const int* __restrict__ nid, const __half* __restrict__ WkjT,
                const float* __restrict__ bkj, const float* __restrict__ Wrbf,
                const float* __restrict__ lrbf0, __half* __restrict__ xkj,
                __half* __restrict__ g0){
  extern __shared__ char sm[];
  int tid = threadIdx.x;
  long e0 = (long)blockIdx.x * EROWS;
  for(int c=tid;c<2048;c+=512){
    int i=c>>4, cc=c&15;
    float4 v = *(const float4*)(WkjT + i*128 + cc*8);
    *(float4*)(sm + PRE_B + ((i*256+cc*16)^((i&7)<<4))) = v;
  }
  __half* rbfp = (__half*)(sm + PRE_RBF);   // [128][40], k<6 real
  for(int c=tid;c<4096;c+=512){
    int r=c>>5, k=c&31; long e=e0+r;
    rbfp[r*40+k] = (k<NRR && e<NE) ? __float2half(rbf[e*NRR+k]) : __float2half(0.f);
  }
  __half* wrt = (__half*)(sm + PRE_WR);     // wrbfT [h][40]
  __half* lst = (__half*)(sm + PRE_LS);     // ls0T  [h][40]
  for(int c=tid;c<4096;c+=512){
    int i=c>>5, k=c&31;
    wrt[i*40+k] = (k<NRR) ? __float2half(Wrbf[k*HD+i])  : __float2half(0.f);
    lst[i*40+k] = (k<NRR) ? __float2half(lrbf0[k*HD+i]) : __float2half(0.f);
  }
  int* nids=(int*)(sm+PRE_NID);
  if (tid < EROWS){ long e=e0+tid; nids[tid]=(e<NE)? nid[e] : 0; }
  __syncthreads();
  int lane=tid&63, wid=tid>>6, wr=wid>>1, wc=wid&1;
  // main GEMM: A direct from global
  f16x8 af[2][4];
  #pragma unroll
  for(int rt=0;rt<2;rt++){
    long e = e0 + wr*32 + rt*16 + (lane&15);
    const __half* arow = xh + e*HD + (lane>>4)*8;
    #pragma unroll
    for(int ks=0;ks<4;ks++){
      if(e<NE) af[rt][ks] = *(const f16x8*)(arow + ks*32);
      else     af[rt][ks] = (f16x8){0,0,0,0,0,0,0,0};
    }
  }
  f32x4 accM[2][4];
  #pragma unroll
  for(int rt=0;rt<2;rt++){
    #pragma unroll
    for(int ct=0;ct<4;ct++) accM[rt][ct]=(f32x4){0.f,0.f,0.f,0.f};
  }
  #pragma unroll
  for(int ct=0;ct<4;ct++){
    int i = wc*64 + ct*16 + (lane&15);
    #pragma unroll
    for(int ks=0;ks<4;ks++){
      f16x8 b = *(const f16x8*)(sm + PRE_B + ((i*256 + (ks*4+(lane>>4))*16)^((i&7)<<4)));
      accM[0][ct] = __builtin_amdgcn_mfma_f32_16x16x32_f16(af[0][ks], b, accM[0][ct], 0,0,0);
      accM[1][ct] = __builtin_amdgcn_mfma_f32_16x16x32_f16(af[1][ks], b, accM[1][ct], 0,0,0);
    }
  }
  // rbf GEMMs (K=32, one ks): R2 = rbf@Wrbf, GATE = rbf@lrbf0
  f16x8 arf[2];
  #pragma unroll
  for(int rt=0;rt<2;rt++)
    arf[rt] = *(const f16x8*)&rbfp[(wr*32 + rt*16 + (lane&15))*40 + (lane>>4)*8];
  f32x4 accR[2][4], accG[2][4];
  #pragma unroll
  for(int rt=0;rt<2;rt++){
    #pragma unroll
    for(int ct=0;ct<4;ct++){ accR[rt][ct]=(f32x4){0.f,0.f,0.f,0.f};
                             accG[rt][ct]=(f32x4){0.f,0.f,0.f,0.f}; }
  }
  #pragma unroll
  for(int ct=0;ct<4;ct++){
    int i = wc*64 + ct*16 + (lane&15);
    f16x8 bw = *(const f16x8*)&wrt[i*40 + (lane>>4)*8];
    f16x8 bl = *(const f16x8*)&lst[i*40 + (lane>>4)*8];
    #pragma unroll
    for(int rt=0;rt<2;rt++){
      accR[rt][ct] = __builtin_amdgcn_mfma_f32_16x16x32_f16(arf[rt], bw, accR[rt][ct], 0,0,0);
      accG[rt][ct] = __builtin_amdgcn_mfma_f32_16x16x32_f16(arf[rt], bl, accG[rt][ct], 0,0,0);
    }
  }
  #pragma unroll
  for(int rt=0;rt<2;rt++){
    #pragma unroll
    for(int j=0;j<4;j++){
      int rloc = wr*32 + rt*16 + (lane>>4)*4 + j;
      long e = e0 + rloc;
      bool ok = (e<NE);
      int nb = nids[rloc];
      #pragma unroll
      for(int ct=0;ct<4;ct++){
        int h = wc*64 + ct*16 + (lane&15);
        float v = silu_f(accM[rt][ct][j] + bkj[h]);
        float xval = ok ? __half2float(xh[e*HD + h]) : 0.f;
        float w1 = v*accR[rt][ct][j];
        float w2 = accG[rt][ct][j]*xval;
        float p1 = __shfl_xor(w1, 1, 64);
        float p2 = __shfl_xor(w2, 1, 64);
        if(ok && !(lane&1)){
          *(__half2*)(xkj + e*HD + h) = __floats2half2_rn(w1, p1);
          pk_add((__half2*)(g0 + (long)nb*HD + h), w2, p2);
        }
      }
    }
  }
}

// ================= k_triplet_mfma (r17, unchanged) =================
#define TROWS 128
#define OFF_BUF 0
#define OFF_SP 49152
#define OFF_KJ 51200
#define OFF_JI 51712
#define OFF_WSB 52224
#define SH_TRIP 53568
__global__ __launch_bounds__(512,4)
void k_triplet_mfma(const __half* __restrict__ xkj, const float* __restrict__ sbf,
                    const float* __restrict__ Wsbf,
                    const int* __restrict__ ikj, const int* __restrict__ iji,
                    const __half* __restrict__ WB2, __half* __restrict__ agg){
  extern __shared__ char sm[];
  int tid = threadIdx.x;
  long t0 = (long)blockIdx.x * TROWS;
  int* kjs = (int*)(sm + OFF_KJ);
  int* jis = (int*)(sm + OFF_JI);
  if (tid < TROWS){
    int ok = (t0 + tid) < NT;
    kjs[tid] = ok ? ikj[t0+tid] : 0;
    jis[tid] = ok ? iji[t0+tid] : -1;
  }
  float* sbuf = (float*)(sm + OFF_BUF);
  for(int q=tid;q<TROWS*NSNRD;q+=512){
    long t = t0 + q/NSNRD;
    sbuf[q] = (t<NT) ? sbf[t*NSNRD + q%NSNRD] : 0.f;
  }
  float* wsb = (float*)(sm + OFF_WSB);
  for(int q=tid;q<NSNRD*NBB;q+=512) wsb[q]=Wsbf[q];
  __syncthreads();
  __half* spl = (__half*)(sm + OFF_SP);
  {
    int r = tid>>2, j0 = (tid&3)*2;
    float a0=0.f,a1=0.f;
    for(int q=0;q<NSNRD;q++){
      float v = sbuf[r*NSNRD+q];
      a0 += v*wsb[q*NBB+j0];
      a1 += v*wsb[q*NBB+j0+1];
    }
    spl[r*NBB+j0]=__float2half(a0); spl[r*NBB+j0+1]=__float2half(a1);
  }
  __syncthreads();
  for(int c=tid;c<TROWS*16;c+=512){
    int w = c>>4, cc = c&15;
    float4 v = *(const float4*)(xkj + (long)kjs[w]*HD + cc*8);
    *(float4*)(sm + OFF_BUF + ((w*256 + cc*16)^((w&7)<<4))) = v;
  }
  __syncthreads();
  int lane = tid & 63;
  int wid = tid>>6, wr = wid>>1, wc = wid&1;
  f16x8 au[2][4];
  #pragma unroll
  for(int rt=0;rt<2;rt++){
    int w = wr*32 + rt*16 + (lane&15);
    #pragma unroll
    for(int ks=0;ks<4;ks++)
      au[rt][ks] = *(const f16x8*)(sm + OFF_BUF + ((w*256 + ks*64 + (lane>>4)*16)^((w&7)<<4)));
  }
  __syncthreads();
  #pragma unroll
  for(int u=0;u<2;u++){
    int c = u*512 + tid;
    int i = c>>3, lc = (c&7) ^ (i&7);
    gload16(WB2 + i*128 + lc*8,
            sm + OFF_BUF + u*8192 + (tid>>6)*1024);
  }
  #pragma unroll
  for(int u=0;u<2;u++){
    int c = u*512 + tid;
    int i = c>>3, lc = (c&7) ^ (i&7);
    gload16(WB2 + i*128 + 64 + lc*8,
            sm + OFF_BUF + 16384 + u*8192 + (tid>>6)*1024);
  }
  f32x4 acc[2][4];
  #pragma unroll
  for(int rt=0;rt<2;rt++){
    #pragma unroll
    for(int ct=0;ct<4;ct++) acc[rt][ct] = (f32x4){0.f,0.f,0.f,0.f};
  }
  _Float16 sr[2];
  #pragma unroll
  for(int p=0;p<16;p++){
    int jb = p>>1, h = p&1;
    if(h==0){
      #pragma unroll
      for(int rt=0;rt<2;rt++)
        sr[rt] = *(const _Float16*)&spl[(wr*32 + rt*16 + (lane&15))*NBB + jb];
    }
    if(p<15) asm volatile("s_waitcnt vmcnt(2)" ::: "memory");
    else     asm volatile("s_waitcnt vmcnt(0)" ::: "memory");
    __builtin_amdgcn_s_barrier();
    asm volatile("" ::: "memory");
    if(p+2 < 16){
      int np = p+2, njb = np>>1, nh = np&1;
      #pragma unroll
      for(int u=0;u<2;u++){
        int c = u*512 + tid;
        int i = c>>3, lc = (c&7) ^ (i&7);
        gload16(WB2 + njb*16384 + i*128 + nh*64 + lc*8,
                sm + OFF_BUF + ((p+2)%3)*16384 + u*8192 + (tid>>6)*1024);
      }
    }
    const char* bbase = sm + OFF_BUF + (p%3)*16384;
    #pragma unroll
    for(int ksl=0;ksl<2;ksl++){
      int ks = h*2 + ksl;
      f16x8 as2[2];
      #pragma unroll
      for(int rt=0;rt<2;rt++){
        #pragma unroll
        for(int j=0;j<8;j++) as2[rt][j] = au[rt][ks][j]*sr[rt];
      }
      #pragma unroll
      for(int ct=0;ct<4;ct++){
        int it = wc*64 + ct*16 + (lane&15);
        int chunk = (ksl*4 + (lane>>4)) ^ (it&7);
        f16x8 b = *(const f16x8*)(bbase + it*128 + chunk*16);
        #pragma unroll
        for(int rt=0;rt<2;rt++)
          acc[rt][ct] = __builtin_amdgcn_mfma_f32_16x16x32_f16(as2[rt], b, acc[rt][ct], 0,0,0);
      }
    }
  }
  #pragma unroll
  for(int rt=0;rt<2;rt++){
    #pragma unroll
    for(int r=0;r<4;r++){
      int w = wr*32 + rt*16 + (lane>>4)*4 + r;
      int ji = jis[w];
      #pragma unroll
      for(int ct=0;ct<4;ct++){
        float v = acc[rt][ct][r];
        float p = __shfl_xor(v, 1, 64);
        if (ji >= 0 && !(lane&1))
          pk_add((__half2*)(agg + (long)ji*HD + wc*64 + ct*16 + (lane&15)), v, p);
      }
    }
  }
}

// ================= k_edge_post (r17, unchanged) =================
#define PO_A 0
#define PO_B 32768
#define PO_RBF 65536
#define PO_LS 68608
#define PO_NID 71680
#define SH_POST 72192
__global__ __launch_bounds__(512,4)
void k_edge_post(const __half* __restrict__ xh, const float* __restrict__ rbf,
                 const __half* __restrict__ aggh, const int* __restrict__ nid,
                 const __half* __restrict__ WjiT, const float* __restrict__ bji,
                 const __half* __restrict__ WlinT, const float* __restrict__ blin,
                 const float* __restrict__ lrbf1, __half* __restrict__ g1){
  extern __shared__ char sm[];
  int tid = threadIdx.x;
  long e0 = (long)blockIdx.x * EROWS;
  for(int c=tid;c<2048;c+=512){
    int i=c>>4, cc=c&15;
    float4 v = *(const float4*)(WjiT + i*128 + cc*8);
    *(float4*)(sm + PO_B + ((i*256+cc*16)^((i&7)<<4))) = v;
  }
  for(int c=tid;c<2048;c+=512){
    int r=c>>4, cc=c&15; long e=e0+r;
    float4 v = (e<NE) ? *(const float4*)(xh + e*HD + cc*8)
                      : (float4){0.f,0.f,0.f,0.f};
    *(float4*)(sm + PO_A + ((r*256+cc*16)^((r&7)<<4))) = v;
  }
  float* rbft=(float*)(sm+PO_RBF);
  for(int q=tid;q<EROWS*NRR;q+=512){ long e=e0+q/NRR; rbft[q]=(e<NE)? rbf[e*NRR + q%NRR] : 0.f; }
  float* ls1=(float*)(sm+PO_LS);
  for(int q=tid;q<NRR*HD;q+=512) ls1[q]=lrbf1[q];
  int* nids=(int*)(sm+PO_NID);
  if (tid < EROWS){ long e=e0+tid; nids[tid]=(e<NE)? nid[e] : 0; }
  __syncthreads();
  int lane=tid&63, wid=tid>>6, wr=wid>>1, wc=wid&1;
  f16x8 af[2][4];
  #pragma unroll
  for(int rt=0;rt<2;rt++){
    int r = wr*32 + rt*16 + (lane&15);
    #pragma unroll
    for(int ks=0;ks<4;ks++)
      af[rt][ks] = *(const f16x8*)(sm + PO_A + ((r*256 + (ks*4+(lane>>4))*16)^((r&7)<<4)));
  }
  f32x4 acc[2][4];
  #pragma unroll
  for(int rt=0;rt<2;rt++){
    #pragma unroll
    for(int ct=0;ct<4;ct++) acc[rt][ct]=(f32x4){0.f,0.f,0.f,0.f};
  }
  #pragma unroll
  for(int ct=0;ct<4;ct++){
    int i = wc*64 + ct*16 + (lane&15);
    #pragma unroll
    for(int ks=0;ks<4;ks++){
      f16x8 b = *(const f16x8*)(sm + PO_B + ((i*256 + (ks*4+(lane>>4))*16)^((i&7)<<4)));
      acc[0][ct] = __builtin_amdgcn_mfma_f32_16x16x32_f16(af[0][ks], b, acc[0][ct], 0,0,0);
      acc[1][ct] = __builtin_amdgcn_mfma_f32_16x16x32_f16(af[1][ks], b, acc[1][ct], 0,0,0);
    }
  }
  __syncthreads();
  #pragma unroll
  for(int rt=0;rt<2;rt++){
    #pragma unroll
    for(int j=0;j<4;j++){
      int rloc = wr*32 + rt*16 + (lane>>4)*4 + j;
      long e = e0 + rloc;
      #pragma unroll
      for(int ct=0;ct<4;ct++){
        int h = wc*64 + ct*16 + (lane&15);
        float v = silu_f(acc[rt][ct][j] + bji[h]);
        v += (e<NE) ? __half2float(aggh[e*HD + h]) : 0.f;
        int byo = ((rloc*256 + (h>>3)*16)^((rloc&7)<<4)) + (h&7)*2;
        *(__half*)(sm + PO_A + byo) = __float2half(v);
      }
    }
  }
  for(int c=tid;c<2048;c+=512){
    int i=c>>4, cc=c&15;
    float4 v = *(const float4*)(WlinT + i*128 + cc*8);
    *(float4*)(sm + PO_B + ((i*256+cc*16)^((i&7)<<4))) = v;
  }
  __syncthreads();
  f16x8 af2[2][4];
  #pragma unroll
  for(int rt=0;rt<2;rt++){
    int r = wr*32 + rt*16 + (lane&15);
    #pragma unroll
    for(int ks=0;ks<4;ks++)
      af2[rt][ks] = *(const f16x8*)(sm + PO_A + ((r*256 + (ks*4+(lane>>4))*16)^((r&7)<<4)));
  }
  f32x4 acc2[2][4];
  #pragma unroll
  for(int rt=0;rt<2;rt++){
    #pragma unroll
    for(int ct=0;ct<4;ct++) acc2[rt][ct]=(f32x4){0.f,0.f,0.f,0.f};
  }
  #pragma unroll
  for(int ct=0;ct<4;ct++){
    int i = wc*64 + ct*16 + (lane&15);
    #pragma unroll
    for(int ks=0;ks<4;ks++){
      f16x8 b = *(const f16x8*)(sm + PO_B + ((i*256 + (ks*4+(lane>>4))*16)^((i&7)<<4)));
      acc2[0][ct] = __builtin_amdgcn_mfma_f32_16x16x32_f16(af2[0][ks], b, acc2[0][ct], 0,0,0);
      acc2[1][ct] = __builtin_amdgcn_mfma_f32_16x16x32_f16(af2[1][ks], b, acc2[1][ct], 0,0,0);
    }
  }
  #pragma unroll
  for(int rt=0;rt<2;rt++){
    #pragma unroll
    for(int j=0;j<4;j++){
      int rloc = wr*32 + rt*16 + (lane>>4)*4 + j;
      long e = e0 + rloc;
      bool ok = (e<NE);
      int nb = nids[rloc];
      #pragma unroll
      for(int ct=0;ct<4;ct++){
        int h = wc*64 + ct*16 + (lane&15);
        float x2 = silu_f(acc2[rt][ct][j] + blin[h]);
        float gate = 0.f;
        #pragma unroll
        for(int q=0;q<NRR;q++) gate += rbft[rloc*NRR+q]*ls1[q*HD+h];
        float w = gate*x2;
        float p = __shfl_xor(w, 1, 64);
        if(ok && !(lane&1))
          pk_add((__half2*)(g1 + (long)nb*HD + h), w, p);
      }
    }
  }
}

// ================= k_mlp_chain (r17, unchanged) ====
#define SH_MLPC 65536
__global__ __launch_bounds__(512,4)
void k_mlp_chain(const __half* __restrict__ g0, const __half* __restrict__ g1,
                 const __half* __restrict__ wo6, const float* __restrict__ olb,
                 float* __restrict__ s0, float* __restrict__ s1){
  extern __shared__ char sm[];
  int tid = threadIdx.x;
  int nblk = (NN+EROWS-1)/EROWS;
  int which = blockIdx.x / nblk;
  long r0 = (long)(blockIdx.x % nblk) * EROWS;
  const __half* gin = which ? g1 : g0;
  float* s = which ? s1 : s0;
  for(int c=tid;c<2048;c+=512){
    int r=c>>4, cc=c&15; long rr=r0+r;
    float4 v;
    if(rr<NN) v = *(const float4*)(gin + rr*HD + cc*8);
    else      v = (float4){0.f,0.f,0.f,0.f};
    *(float4*)(sm + ((r*256+cc*16)^((r&7)<<4))) = v;
  }
  int lane=tid&63, wid=tid>>6, wr=wid>>1, wc=wid&1;
  for(int L=0; L<3; ++L){
    const __half* WT = wo6 + (which*3+L)*16384;
    const float* b   = olb + (which*3+L)*128;
    for(int c=tid;c<2048;c+=512){
      int i=c>>4, cc=c&15;
      float4 v = *(const float4*)(WT + i*128 + cc*8);
      *(float4*)(sm + 32768 + ((i*256+cc*16)^((i&7)<<4))) = v;
    }
    __syncthreads();
    f16x8 af[2][4];
    #pragma unroll
    for(int rt=0;rt<2;rt++){
      int r = wr*32 + rt*16 + (lane&15);
      #pragma unroll
      for(int ks=0;ks<4;ks++)
        af[rt][ks] = *(const f16x8*)(sm + ((r*256 + (ks*4+(lane>>4))*16)^((r&7)<<4)));
    }
    f32x4 acc[2][4];
    #pragma unroll
    for(int rt=0;rt<2;rt++){
      #pragma unroll
      for(int ct=0;ct<4;ct++) acc[rt][ct]=(f32x4){0.f,0.f,0.f,0.f};
    }
    #pragma unroll
    for(int ct=0;ct<4;ct++){
      int i = wc*64 + ct*16 + (lane&15);
      #pragma unroll
      for(int ks=0;ks<4;ks++){
        f16x8 bfr = *(const f16x8*)(sm + 32768 + ((i*256 + (ks*4+(lane>>4))*16)^((i&7)<<4)));
        acc[0][ct] = __builtin_amdgcn_mfma_f32_16x16x32_f16(af[0][ks], bfr, acc[0][ct], 0,0,0);
        acc[1][ct] = __builtin_amdgcn_mfma_f32_16x16x32_f16(af[1][ks], bfr, acc[1][ct], 0,0,0);
      }
    }
    __syncthreads();
    if(L < 2){
      #pragma unroll
      for(int rt=0;rt<2;rt++){
        #pragma unroll
        for(int j=0;j<4;j++){
          int rloc = wr*32 + rt*16 + (lane>>4)*4 + j;
          #pragma unroll
          for(int ct=0;ct<4;ct++){
            int h = wc*64 + ct*16 + (lane&15);
            float v = silu_f(acc[rt][ct][j] + b[h]);
            int byo = ((rloc*256 + (h>>3)*16)^((rloc&7)<<4)) + (h&7)*2;
            *(__half*)(sm + byo) = __float2half(v);
          }
        }
      }
    } else {
      float vsum[4];
      #pragma unroll
      for(int ct=0;ct<4;ct++) vsum[ct]=0.f;
      #pragma unroll
      for(int rt=0;rt<2;rt++){
        #pragma unroll
        for(int j=0;j<4;j++){
          int rloc = wr*32 + rt*16 + (lane>>4)*4 + j;
          long rr = r0 + rloc;
          #pragma unroll
          for(int ct=0;ct<4;ct++){
            int h = wc*64 + ct*16 + (lane&15);
            float v = (rr<NN) ? silu_f(acc[rt][ct][j] + b[h]) : 0.f;
            vsum[ct] += v;
          }
        }
      }
      #pragma unroll
      for(int ct=0;ct<4;ct++){
        vsum[ct] += __shfl_xor(vsum[ct], 16, 64);
        vsum[ct] += __shfl_xor(vsum[ct], 32, 64);
      }
      if((lane>>4)==0){
        #pragma unroll
        for(int ct=0;ct<4;ct++)
          atomicAdd(&s[wc*64 + ct*16 + (lane&15)], vsum[ct]);
      }
    }
  }
}

// ---- final readout ----
__global__ void k_readout(const float* __restrict__ s0, const float* __restrict__ s1,
                          const float* __restrict__ OL, float* __restrict__ out){
  int o = threadIdx.x;
  float acc=0.f;
  for(int h=0;h<HD;h++) acc += s0[h]*OL[h*HD+o] + s1[h]*OL[HD*HD + h*HD+o];
  out[o] = acc;
}

extern "C" void kernel_launch(void* const* d_in, const int* in_sizes, int n_in,
                              void* d_out, int out_size, void* d_ws, size_t ws_size,
                              hipStream_t stream) {
  const float* x     = (const float*)d_in[0];
  const float* rbf   = (const float*)d_in[1];
  const float* sbf   = (const float*)d_in[2];
  const int*   nid   = (const int*)d_in[3];
  const int*   ikj   = (const int*)d_in[4];
  const int*   iji   = (const int*)d_in[5];
  const float* W_rbf = (const float*)d_in[6];
  const float* W_sbf = (const float*)d_in[7];
  const float* W_kj  = (const float*)d_in[8];
  const float* b_kj  = (const float*)d_in[9];
  const float* W_ji  = (const float*)d_in[10];
  const float* b_ji  = (const float*)d_in[11];
  const float* W_bil = (const float*)d_in[12];
  const float* W_lin = (const float*)d_in[13];
  const float* b_lin = (const float*)d_in[14];
  const float* olrbf = (const float*)d_in[15];
  const float* olW   = (const float*)d_in[16];
  const float* olb   = (const float*)d_in[17];
  const float* olin  = (const float*)d_in[18];
  float* out = (float*)d_out;

  size_t off = 0;
  auto alloc = [&](size_t bytes)->size_t{ size_t r = off; off = (off + bytes + 255) & ~(size_t)255; return r; };
  size_t o_xkj  = alloc((size_t)NE*HD*2);
  size_t o_xh   = alloc((size_t)NE*HD*2);
  size_t o_agg  = alloc((size_t)NE*HD*2);
  size_t o_wb2  = alloc((size_t)NBB*HD*HD*2);
  size_t o_wkjT = alloc((size_t)HD*HD*2);
  size_t o_wjiT = alloc((size_t)HD*HD*2);
  size_t o_wlinT= alloc((size_t)HD*HD*2);
  size_t o_wo6  = alloc((size_t)6*HD*HD*2);
  size_t o_g0   = alloc((size_t)NN*HD*2);
  size_t o_g1   = alloc((size_t)NN*HD*2);
  size_t o_s0   = alloc(512);
  size_t o_s1   = alloc(512);
  if (off > ws_size) return;
  char* ws = (char*)d_ws;
  __half* xkj  = (__half*)(ws + o_xkj);
  __half* xh   = (__half*)(ws + o_xh);
  __half* agg  = (__half*)(ws + o_agg);
  __half* wb2  = (__half*)(ws + o_wb2);
  __half* wkjT = (__half*)(ws + o_wkjT);
  __half* wjiT = (__half*)(ws + o_wjiT);
  __half* wlinT= (__half*)(ws + o_wlinT);
  __half* wo6  = (__half*)(ws + o_wo6);
  __half* g0   = (__half*)(ws + o_g0);
  __half* g1   = (__half*)(ws + o_g1);
  float* s0    = (float*)(ws + o_s0);
  float* s1    = (float*)(ws + o_s1);

  hipFuncSetAttribute((const void*)k_edge_pre,     hipFuncAttributeMaxDynamicSharedMemorySize, SH_PRE);
  hipFuncSetAttribute((const void*)k_edge_post,    hipFuncAttributeMaxDynamicSharedMemorySize, SH_POST);
  hipFuncSetAttribute((const void*)k_triplet_mfma, hipFuncAttributeMaxDynamicSharedMemorySize, SH_TRIP);
  hipFuncSetAttribute((const void*)k_mlp_chain,    hipFuncAttributeMaxDynamicSharedMemorySize, SH_MLPC);

  hipMemsetAsync(agg, 0, (size_t)NE*HD*2, stream);
  hipMemsetAsync(g0,  0, (size_t)NN*HD*2, stream);
  hipMemsetAsync(g1,  0, (size_t)NN*HD*2, stream);
  hipMemsetAsync(s0,  0, 512, stream);
  hipMemsetAsync(s1,  0, 512, stream);

  k_x16<<<(int)(((long)NE*HD/8 + 255)/256),256,0,stream>>>(x, xh);
  k_prep<<<1088,256,0,stream>>>(W_bil, wb2, W_kj, W_ji, W_lin, wkjT, wjiT, wlinT, olW, wo6);

  k_edge_pre<<<(NE+EROWS-1)/EROWS,512,SH_PRE,stream>>>(xh, rbf, nid, wkjT, b_kj, W_rbf,
                                                       olrbf, xkj, g0);
  k_triplet_mfma<<<(NT+TROWS-1)/TROWS,512,SH_TRIP,stream>>>(xkj, sbf, W_sbf, ikj, iji, wb2, agg);
  k_edge_post<<<(NE+EROWS-1)/EROWS,512,SH_POST,stream>>>(xh, rbf, agg, nid, wjiT, b_ji,
                                                         wlinT, b_lin, olrbf + NRR*HD, g1);

  int mlpg = (NN+EROWS-1)/EROWS;
  k_mlp_chain<<<2*mlpg,512,SH_MLPC,stream>>>(g0, g1, wo6, olb, s0, s1);

  k_readout<<<1,128,0,stream>>>(s0, s1, olin, out);
}

// Round 19
// 732.745 us; speedup vs baseline: 1.0421x; 1.0421x over previous
//
#include <hip/hip_runtime.h>
#include <hip/hip_fp16.h>

#define NN 20000
#define NE 300000
#define NT 500000
#define HD 128
#define NRR 6
#define NSNRD 42
#define NBB 8

using f16x8 = __attribute__((ext_vector_type(8))) _Float16;
using f32x4 = __attribute__((ext_vector_type(4))) float;

__device__ __forceinline__ float silu_f(float v){ return v / (1.f + __expf(-v)); }

__device__ __forceinline__ void pk_add(__half2* p, float lo, float hi){
  __half2 h = __floats2half2_rn(lo, hi);
  unsigned int b = *reinterpret_cast<unsigned int*>(&h);
  asm volatile("global_atomic_pk_add_f16 %0, %1, off" :: "v"(p), "v"(b) : "memory");
}

__device__ __forceinline__ void gload16(const void* g, char* lds_dst){
  __builtin_amdgcn_global_load_lds(
    (const __attribute__((address_space(1))) void*)g,
    (__attribute__((address_space(3))) void*)lds_dst, 16, 0, 0);
}

// ---- x fp32->fp16 + all weight prep, ONE launch ----
#define XBLK 18750
__global__ void k_prep(const float* __restrict__ x, __half* __restrict__ xh,
                       const float* __restrict__ Wb, __half* __restrict__ WB2,
                       const float* __restrict__ Wkj, const float* __restrict__ Wji,
                       const float* __restrict__ Wlin, __half* __restrict__ WkjT,
                       __half* __restrict__ WjiT, __half* __restrict__ WlinT,
                       const float* __restrict__ olW, __half* __restrict__ wo6){
  int bid = blockIdx.x, tid = threadIdx.x;
  if(bid < XBLK){                                 // x -> fp16
    long i = ((long)bid*256 + tid)*8;
    if(i < (long)NE*HD){
      float4 a = *(const float4*)(x+i), b = *(const float4*)(x+i+4);
      __half h8[8];
      h8[0]=__float2half(a.x); h8[1]=__float2half(a.y);
      h8[2]=__float2half(a.z); h8[3]=__float2half(a.w);
      h8[4]=__float2half(b.x); h8[5]=__float2half(b.y);
      h8[6]=__float2half(b.z); h8[7]=__float2half(b.w);
      *(float4*)(xh+i) = *(float4*)h8;
    }
  } else if(bid < XBLK+512){                      // W_bil [i][jb][l] -> [jb][i][l]
    int idx = (bid-XBLK)*256 + tid;
    int l = idx & 127, i = (idx>>7) & 127, jb = idx>>14;
    WB2[jb*16384 + i*128 + l] = __float2half(Wb[i*1024 + jb*128 + l]);
  } else if(bid < XBLK+704){                      // W_kj/W_ji/W_lin -> [i][k]
    int idx = (bid-XBLK-512)*256 + tid;
    int which = idx>>14, rem = idx & 16383;
    int i = rem>>7, k = rem & 127;
    const float* src = which==0 ? Wkj : (which==1 ? Wji : Wlin);
    __half* dst = which==0 ? WkjT : (which==1 ? WjiT : WlinT);
    dst[rem] = __float2half(src[k*HD + i]);
  } else {                                        // olW [6][k][i] -> [6][i][k]
    int idx = (bid-XBLK-704)*256 + tid;
    int lw = idx>>14, rem = idx & 16383;
    int i = rem>>7, k = rem & 127;
    wo6[lw*16384 + rem] = __float2half(olW[lw*16384 + k*HD + i]);
  }
}

// ================= k_edge_pre (512 thr, 4x2 wave grid) =================
#define EROWS 128
#define PRE_A 0
#define PRE_B 32768
#define PRE_RBF 65536
#define PRE_WR 68608
#define PRE_LS 71680
#define PRE_NID 74752
#define SH_PRE 75264
__global__ __launch_bounds__(512,4)
void k_edge_pre(const __half* __restrict__ xh, const float* __restrict__ rbf,
                const int* __restrict__ nid, const __half* __restrict__ WkjT,
                const float* __restrict__ bkj, const float* __restrict__ Wrbf,
                const float* __restrict__ lrbf0, __half* __restrict__ xkj,
                __half* __restrict__ g0){
  extern __shared__ char sm[];
  int tid = threadIdx.x;
  long e0 = (long)blockIdx.x * EROWS;
  for(int c=tid;c<2048;c+=512){
    int i=c>>4, cc=c&15;
    float4 v = *(const float4*)(WkjT + i*128 + cc*8);
    *(float4*)(sm + PRE_B + ((i*256+cc*16)^((i&7)<<4))) = v;
  }
  for(int c=tid;c<2048;c+=512){
    int r=c>>4, cc=c&15; long e=e0+r;
    float4 v = (e<NE) ? *(const float4*)(xh + e*HD + cc*8)
                      : (float4){0.f,0.f,0.f,0.f};
    *(float4*)(sm + PRE_A + ((r*256+cc*16)^((r&7)<<4))) = v;
  }
  float* rbft=(float*)(sm+PRE_RBF);
  for(int q=tid;q<EROWS*NRR;q+=512){ long e=e0+q/NRR; rbft[q]=(e<NE)? rbf[e*NRR + q%NRR] : 0.f; }
  float* wrbf=(float*)(sm+PRE_WR);
  for(int q=tid;q<NRR*HD;q+=512) wrbf[q]=Wrbf[q];
  float* ls0=(float*)(sm+PRE_LS);
  for(int q=tid;q<NRR*HD;q+=512) ls0[q]=lrbf0[q];
  int* nids=(int*)(sm+PRE_NID);
  if (tid < EROWS){ long e=e0+tid; nids[tid]=(e<NE)? nid[e] : 0; }
  __syncthreads();
  int lane=tid&63, wid=tid>>6, wr=wid>>1, wc=wid&1;
  f16x8 af[2][4];
  #pragma unroll
  for(int rt=0;rt<2;rt++){
    int r = wr*32 + rt*16 + (lane&15);
    #pragma unroll
    for(int ks=0;ks<4;ks++)
      af[rt][ks] = *(const f16x8*)(sm + PRE_A + ((r*256 + (ks*4+(lane>>4))*16)^((r&7)<<4)));
  }
  f32x4 acc[2][4];
  #pragma unroll
  for(int rt=0;rt<2;rt++){
    #pragma unroll
    for(int ct=0;ct<4;ct++) acc[rt][ct]=(f32x4){0.f,0.f,0.f,0.f};
  }
  #pragma unroll
  for(int ct=0;ct<4;ct++){
    int i = wc*64 + ct*16 + (lane&15);
    #pragma unroll
    for(int ks=0;ks<4;ks++){
      f16x8 b = *(const f16x8*)(sm + PRE_B + ((i*256 + (ks*4+(lane>>4))*16)^((i&7)<<4)));
      acc[0][ct] = __builtin_amdgcn_mfma_f32_16x16x32_f16(af[0][ks], b, acc[0][ct], 0,0,0);
      acc[1][ct] = __builtin_amdgcn_mfma_f32_16x16x32_f16(af[1][ks], b, acc[1][ct], 0,0,0);
    }
  }
  #pragma unroll
  for(int rt=0;rt<2;rt++){
    #pragma unroll
    for(int j=0;j<4;j++){
      int rloc = wr*32 + rt*16 + (lane>>4)*4 + j;
      long e = e0 + rloc;
      bool ok = (e<NE);
      int nb = nids[rloc];
      #pragma unroll
      for(int ct=0;ct<4;ct++){
        int h = wc*64 + ct*16 + (lane&15);
        float v = silu_f(acc[rt][ct][j] + bkj[h]);
        float r2=0.f, gate=0.f;
        #pragma unroll
        for(int q=0;q<NRR;q++){
          float rb = rbft[rloc*NRR+q];
          r2   += rb*wrbf[q*HD+h];
          gate += rb*ls0[q*HD+h];
        }
        float xval = __half2float(*(const __half*)(sm + PRE_A +
                       ((rloc*256 + (h>>3)*16)^((rloc&7)<<4)) + (h&7)*2));
        float w1 = v*r2;
        float w2 = gate*xval;
        float p1 = __shfl_xor(w1, 1, 64);
        float p2 = __shfl_xor(w2, 1, 64);
        if(ok && !(lane&1)){
          *(__half2*)(xkj + e*HD + h) = __floats2half2_rn(w1, p1);
          pk_add((__half2*)(g0 + (long)nb*HD + h), w2, p2);
        }
      }
    }
  }
}

// ================= k_triplet_mfma =================
#define TROWS 128
#define OFF_BUF 0
#define OFF_SP 49152
#define OFF_KJ 51200
#define OFF_JI 51712
#define OFF_WSB 52224
#define SH_TRIP 53568
__global__ __launch_bounds__(512,4)
void k_triplet_mfma(const __half* __restrict__ xkj, const float* __restrict__ sbf,
                    const float* __restrict__ Wsbf,
                    const int* __restrict__ ikj, const int* __restrict__ iji,
                    const __half* __restrict__ WB2, __half* __restrict__ agg){
  extern __shared__ char sm[];
  int tid = threadIdx.x;
  long t0 = (long)blockIdx.x * TROWS;
  int* kjs = (int*)(sm + OFF_KJ);
  int* jis = (int*)(sm + OFF_JI);
  if (tid < TROWS){
    int ok = (t0 + tid) < NT;
    kjs[tid] = ok ? ikj[t0+tid] : 0;
    jis[tid] = ok ? iji[t0+tid] : -1;
  }
  float* sbuf = (float*)(sm + OFF_BUF);
  for(int q=tid;q<TROWS*NSNRD;q+=512){
    long t = t0 + q/NSNRD;
    sbuf[q] = (t<NT) ? sbf[t*NSNRD + q%NSNRD] : 0.f;
  }
  float* wsb = (float*)(sm + OFF_WSB);
  for(int q=tid;q<NSNRD*NBB;q+=512) wsb[q]=Wsbf[q];
  __syncthreads();
  __half* spl = (__half*)(sm + OFF_SP);
  {
    int r = tid>>2, j0 = (tid&3)*2;
    float a0=0.f,a1=0.f;
    for(int q=0;q<NSNRD;q++){
      float v = sbuf[r*NSNRD+q];
      a0 += v*wsb[q*NBB+j0];
      a1 += v*wsb[q*NBB+j0+1];
    }
    spl[r*NBB+j0]=__float2half(a0); spl[r*NBB+j0+1]=__float2half(a1);
  }
  __syncthreads();
  for(int c=tid;c<TROWS*16;c+=512){
    int w = c>>4, cc = c&15;
    float4 v = *(const float4*)(xkj + (long)kjs[w]*HD + cc*8);
    *(float4*)(sm + OFF_BUF + ((w*256 + cc*16)^((w&7)<<4))) = v;
  }
  __syncthreads();
  int lane = tid & 63;
  int wid = tid>>6, wr = wid>>1, wc = wid&1;
  f16x8 au[2][4];
  #pragma unroll
  for(int rt=0;rt<2;rt++){
    int w = wr*32 + rt*16 + (lane&15);
    #pragma unroll
    for(int ks=0;ks<4;ks++)
      au[rt][ks] = *(const f16x8*)(sm + OFF_BUF + ((w*256 + ks*64 + (lane>>4)*16)^((w&7)<<4)));
  }
  __syncthreads();
  #pragma unroll
  for(int u=0;u<2;u++){
    int c = u*512 + tid;
    int i = c>>3, lc = (c&7) ^ (i&7);
    gload16(WB2 + i*128 + lc*8,
            sm + OFF_BUF + u*8192 + (tid>>6)*1024);
  }
  #pragma unroll
  for(int u=0;u<2;u++){
    int c = u*512 + tid;
    int i = c>>3, lc = (c&7) ^ (i&7);
    gload16(WB2 + i*128 + 64 + lc*8,
            sm + OFF_BUF + 16384 + u*8192 + (tid>>6)*1024);
  }
  f32x4 acc[2][4];
  #pragma unroll
  for(int rt=0;rt<2;rt++){
    #pragma unroll
    for(int ct=0;ct<4;ct++) acc[rt][ct] = (f32x4){0.f,0.f,0.f,0.f};
  }
  _Float16 sr[2];
  #pragma unroll
  for(int p=0;p<16;p++){
    int jb = p>>1, h = p&1;
    if(h==0){
      #pragma unroll
      for(int rt=0;rt<2;rt++)
        sr[rt] = *(const _Float16*)&spl[(wr*32 + rt*16 + (lane&15))*NBB + jb];
    }
    if(p<15) asm volatile("s_waitcnt vmcnt(2)" ::: "memory");
    else     asm volatile("s_waitcnt vmcnt(0)" ::: "memory");
    __builtin_amdgcn_s_barrier();
    asm volatile("" ::: "memory");
    if(p+2 < 16){
      int np = p+2, njb = np>>1, nh = np&1;
      #pragma unroll
      for(int u=0;u<2;u++){
        int c = u*512 + tid;
        int i = c>>3, lc = (c&7) ^ (i&7);
        gload16(WB2 + njb*16384 + i*128 + nh*64 + lc*8,
                sm + OFF_BUF + ((p+2)%3)*16384 + u*8192 + (tid>>6)*1024);
      }
    }
    const char* bbase = sm + OFF_BUF + (p%3)*16384;
    #pragma unroll
    for(int ksl=0;ksl<2;ksl++){
      int ks = h*2 + ksl;
      f16x8 as2[2];
      #pragma unroll
      for(int rt=0;rt<2;rt++){
        #pragma unroll
        for(int j=0;j<8;j++) as2[rt][j] = au[rt][ks][j]*sr[rt];
      }
      #pragma unroll
      for(int ct=0;ct<4;ct++){
        int it = wc*64 + ct*16 + (lane&15);
        int chunk = (ksl*4 + (lane>>4)) ^ (it&7);
        f16x8 b = *(const f16x8*)(bbase + it*128 + chunk*16);
        #pragma unroll
        for(int rt=0;rt<2;rt++)
          acc[rt][ct] = __builtin_amdgcn_mfma_f32_16x16x32_f16(as2[rt], b, acc[rt][ct], 0,0,0);
      }
    }
  }
  #pragma unroll
  for(int rt=0;rt<2;rt++){
    #pragma unroll
    for(int r=0;r<4;r++){
      int w = wr*32 + rt*16 + (lane>>4)*4 + r;
      int ji = jis[w];
      #pragma unroll
      for(int ct=0;ct<4;ct++){
        float v = acc[rt][ct][r];
        float p = __shfl_xor(v, 1, 64);
        if (ji >= 0 && !(lane&1))
          pk_add((__half2*)(agg + (long)ji*HD + wc*64 + ct*16 + (lane&15)), v, p);
      }
    }
  }
}

// ================= k_edge_post (512 thr, 4x2 wave grid) =================
#define PO_A 0
#define PO_B 32768
#define PO_RBF 65536
#define PO_LS 68608
#define PO_NID 71680
#define SH_POST 72192
__global__ __launch_bounds__(512,4)
void k_edge_post(const __half* __restrict__ xh, const float* __restrict__ rbf,
                 const __half* __restrict__ aggh, const int* __restrict__ nid,
                 const __half* __restrict__ WjiT, const float* __restrict__ bji,
                 const __half* __restrict__ WlinT, const float* __restrict__ blin,
                 const float* __restrict__ lrbf1, __half* __restrict__ g1){
  extern __shared__ char sm[];
  int tid = threadIdx.x;
  long e0 = (long)blockIdx.x * EROWS;
  for(int c=tid;c<2048;c+=512){
    int i=c>>4, cc=c&15;
    float4 v = *(const float4*)(WjiT + i*128 + cc*8);
    *(float4*)(sm + PO_B + ((i*256+cc*16)^((i&7)<<4))) = v;
  }
  for(int c=tid;c<2048;c+=512){
    int r=c>>4, cc=c&15; long e=e0+r;
    float4 v = (e<NE) ? *(const float4*)(xh + e*HD + cc*8)
                      : (float4){0.f,0.f,0.f,0.f};
    *(float4*)(sm + PO_A + ((r*256+cc*16)^((r&7)<<4))) = v;
  }
  float* rbft=(float*)(sm+PO_RBF);
  for(int q=tid;q<EROWS*NRR;q+=512){ long e=e0+q/NRR; rbft[q]=(e<NE)? rbf[e*NRR + q%NRR] : 0.f; }
  float* ls1=(float*)(sm+PO_LS);
  for(int q=tid;q<NRR*HD;q+=512) ls1[q]=lrbf1[q];
  int* nids=(int*)(sm+PO_NID);
  if (tid < EROWS){ long e=e0+tid; nids[tid]=(e<NE)? nid[e] : 0; }
  __syncthreads();
  int lane=tid&63, wid=tid>>6, wr=wid>>1, wc=wid&1;
  f16x8 af[2][4];
  #pragma unroll
  for(int rt=0;rt<2;rt++){
    int r = wr*32 + rt*16 + (lane&15);
    #pragma unroll
    for(int ks=0;ks<4;ks++)
      af[rt][ks] = *(const f16x8*)(sm + PO_A + ((r*256 + (ks*4+(lane>>4))*16)^((r&7)<<4)));
  }
  f32x4 acc[2][4];
  #pragma unroll
  for(int rt=0;rt<2;rt++){
    #pragma unroll
    for(int ct=0;ct<4;ct++) acc[rt][ct]=(f32x4){0.f,0.f,0.f,0.f};
  }
  #pragma unroll
  for(int ct=0;ct<4;ct++){
    int i = wc*64 + ct*16 + (lane&15);
    #pragma unroll
    for(int ks=0;ks<4;ks++){
      f16x8 b = *(const f16x8*)(sm + PO_B + ((i*256 + (ks*4+(lane>>4))*16)^((i&7)<<4)));
      acc[0][ct] = __builtin_amdgcn_mfma_f32_16x16x32_f16(af[0][ks], b, acc[0][ct], 0,0,0);
      acc[1][ct] = __builtin_amdgcn_mfma_f32_16x16x32_f16(af[1][ks], b, acc[1][ct], 0,0,0);
    }
  }
  __syncthreads();
  #pragma unroll
  for(int rt=0;rt<2;rt++){
    #pragma unroll
    for(int j=0;j<4;j++){
      int rloc = wr*32 + rt*16 + (lane>>4)*4 + j;
      long e = e0 + rloc;
      #pragma unroll
      for(int ct=0;ct<4;ct++){
        int h = wc*64 + ct*16 + (lane&15);
        float v = silu_f(acc[rt][ct][j] + bji[h]);
        v += (e<NE) ? __half2float(aggh[e*HD + h]) : 0.f;
        int byo = ((rloc*256 + (h>>3)*16)^((rloc&7)<<4)) + (h&7)*2;
        *(__half*)(sm + PO_A + byo) = __float2half(v);
      }
    }
  }
  for(int c=tid;c<2048;c+=512){
    int i=c>>4, cc=c&15;
    float4 v = *(const float4*)(WlinT + i*128 + cc*8);
    *(float4*)(sm + PO_B + ((i*256+cc*16)^((i&7)<<4))) = v;
  }
  __syncthreads();
  f16x8 af2[2][4];
  #pragma unroll
  for(int rt=0;rt<2;rt++){
    int r = wr*32 + rt*16 + (lane&15);
    #pragma unroll
    for(int ks=0;ks<4;ks++)
      af2[rt][ks] = *(const f16x8*)(sm + PO_A + ((r*256 + (ks*4+(lane>>4))*16)^((r&7)<<4)));
  }
  f32x4 acc2[2][4];
  #pragma unroll
  for(int rt=0;rt<2;rt++){
    #pragma unroll
    for(int ct=0;ct<4;ct++) acc2[rt][ct]=(f32x4){0.f,0.f,0.f,0.f};
  }
  #pragma unroll
  for(int ct=0;ct<4;ct++){
    int i = wc*64 + ct*16 + (lane&15);
    #pragma unroll
    for(int ks=0;ks<4;ks++){
      f16x8 b = *(const f16x8*)(sm + PO_B + ((i*256 + (ks*4+(lane>>4))*16)^((i&7)<<4)));
      acc2[0][ct] = __builtin_amdgcn_mfma_f32_16x16x32_f16(af2[0][ks], b, acc2[0][ct], 0,0,0);
      acc2[1][ct] = __builtin_amdgcn_mfma_f32_16x16x32_f16(af2[1][ks], b, acc2[1][ct], 0,0,0);
    }
  }
  #pragma unroll
  for(int rt=0;rt<2;rt++){
    #pragma unroll
    for(int j=0;j<4;j++){
      int rloc = wr*32 + rt*16 + (lane>>4)*4 + j;
      long e = e0 + rloc;
      bool ok = (e<NE);
      int nb = nids[rloc];
      #pragma unroll
      for(int ct=0;ct<4;ct++){
        int h = wc*64 + ct*16 + (lane&15);
        float x2 = silu_f(acc2[rt][ct][j] + blin[h]);
        float gate = 0.f;
        #pragma unroll
        for(int q=0;q<NRR;q++) gate += rbft[rloc*NRR+q]*ls1[q*HD+h];
        float w = gate*x2;
        float p = __shfl_xor(w, 1, 64);
        if(ok && !(lane&1))
          pk_add((__half2*)(g1 + (long)nb*HD + h), w, p);
      }
    }
  }
}

// ================= k_mlp_chain: 3 layers + colsum, both blocks, ONE launch ====
#define SH_MLPC 65536
__global__ __launch_bounds__(512,4)
void k_mlp_chain(const __half* __restrict__ g0, const __half* __restrict__ g1,
                 const __half* __restrict__ wo6, const float* __restrict__ olb,
                 float* __restrict__ s0, float* __restrict__ s1){
  extern __shared__ char sm[];
  int tid = threadIdx.x;
  int nblk = (NN+EROWS-1)/EROWS;
  int which = blockIdx.x / nblk;
  long r0 = (long)(blockIdx.x % nblk) * EROWS;
  const __half* gin = which ? g1 : g0;
  float* s = which ? s1 : s0;
  for(int c=tid;c<2048;c+=512){
    int r=c>>4, cc=c&15; long rr=r0+r;
    float4 v;
    if(rr<NN) v = *(const float4*)(gin + rr*HD + cc*8);
    else      v = (float4){0.f,0.f,0.f,0.f};
    *(float4*)(sm + ((r*256+cc*16)^((r&7)<<4))) = v;
  }
  int lane=tid&63, wid=tid>>6, wr=wid>>1, wc=wid&1;
  for(int L=0; L<3; ++L){
    const __half* WT = wo6 + (which*3+L)*16384;
    const float* b   = olb + (which*3+L)*128;
    for(int c=tid;c<2048;c+=512){
      int i=c>>4, cc=c&15;
      float4 v = *(const float4*)(WT + i*128 + cc*8);
      *(float4*)(sm + 32768 + ((i*256+cc*16)^((i&7)<<4))) = v;
    }
    __syncthreads();
    f16x8 af[2][4];
    #pragma unroll
    for(int rt=0;rt<2;rt++){
      int r = wr*32 + rt*16 + (lane&15);
      #pragma unroll
      for(int ks=0;ks<4;ks++)
        af[rt][ks] = *(const f16x8*)(sm + ((r*256 + (ks*4+(lane>>4))*16)^((r&7)<<4)));
    }
    f32x4 acc[2][4];
    #pragma unroll
    for(int rt=0;rt<2;rt++){
      #pragma unroll
      for(int ct=0;ct<4;ct++) acc[rt][ct]=(f32x4){0.f,0.f,0.f,0.f};
    }
    #pragma unroll
    for(int ct=0;ct<4;ct++){
      int i = wc*64 + ct*16 + (lane&15);
      #pragma unroll
      for(int ks=0;ks<4;ks++){
        f16x8 bfr = *(const f16x8*)(sm + 32768 + ((i*256 + (ks*4+(lane>>4))*16)^((i&7)<<4)));
        acc[0][ct] = __builtin_amdgcn_mfma_f32_16x16x32_f16(af[0][ks], bfr, acc[0][ct], 0,0,0);
        acc[1][ct] = __builtin_amdgcn_mfma_f32_16x16x32_f16(af[1][ks], bfr, acc[1][ct], 0,0,0);
      }
    }
    __syncthreads();
    if(L < 2){
      #pragma unroll
      for(int rt=0;rt<2;rt++){
        #pragma unroll
        for(int j=0;j<4;j++){
          int rloc = wr*32 + rt*16 + (lane>>4)*4 + j;
          #pragma unroll
          for(int ct=0;ct<4;ct++){
            int h = wc*64 + ct*16 + (lane&15);
            float v = silu_f(acc[rt][ct][j] + b[h]);
            int byo = ((rloc*256 + (h>>3)*16)^((rloc&7)<<4)) + (h&7)*2;
            *(__half*)(sm + byo) = __float2half(v);
          }
        }
      }
    } else {
      float vsum[4];
      #pragma unroll
      for(int ct=0;ct<4;ct++) vsum[ct]=0.f;
      #pragma unroll
      for(int rt=0;rt<2;rt++){
        #pragma unroll
        for(int j=0;j<4;j++){
          int rloc = wr*32 + rt*16 + (lane>>4)*4 + j;
          long rr = r0 + rloc;
          #pragma unroll
          for(int ct=0;ct<4;ct++){
            int h = wc*64 + ct*16 + (lane&15);
            float v = (rr<NN) ? silu_f(acc[rt][ct][j] + b[h]) : 0.f;
            vsum[ct] += v;
          }
        }
      }
      #pragma unroll
      for(int ct=0;ct<4;ct++){
        vsum[ct] += __shfl_xor(vsum[ct], 16, 64);
        vsum[ct] += __shfl_xor(vsum[ct], 32, 64);
      }
      if((lane>>4)==0){
        #pragma unroll
        for(int ct=0;ct<4;ct++)
          atomicAdd(&s[wc*64 + ct*16 + (lane&15)], vsum[ct]);
      }
    }
  }
}

// ---- final readout ----
__global__ void k_readout(const float* __restrict__ s0, const float* __restrict__ s1,
                          const float* __restrict__ OL, float* __restrict__ out){
  int o = threadIdx.x;
  float acc=0.f;
  for(int h=0;h<HD;h++) acc += s0[h]*OL[h*HD+o] + s1[h]*OL[HD*HD + h*HD+o];
  out[o] = acc;
}

extern "C" void kernel_launch(void* const* d_in, const int* in_sizes, int n_in,
                              void* d_out, int out_size, void* d_ws, size_t ws_size,
                              hipStream_t stream) {
  const float* x     = (const float*)d_in[0];
  const float* rbf   = (const float*)d_in[1];
  const float* sbf   = (const float*)d_in[2];
  const int*   nid   = (const int*)d_in[3];
  const int*   ikj   = (const int*)d_in[4];
  const int*   iji   = (const int*)d_in[5];
  const float* W_rbf = (const float*)d_in[6];
  const float* W_sbf = (const float*)d_in[7];
  const float* W_kj  = (const float*)d_in[8];
  const float* b_kj  = (const float*)d_in[9];
  const float* W_ji  = (const float*)d_in[10];
  const float* b_ji  = (const float*)d_in[11];
  const float* W_bil = (const float*)d_in[12];
  const float* W_lin = (const float*)d_in[13];
  const float* b_lin = (const float*)d_in[14];
  const float* olrbf = (const float*)d_in[15];
  const float* olW   = (const float*)d_in[16];
  const float* olb   = (const float*)d_in[17];
  const float* olin  = (const float*)d_in[18];
  float* out = (float*)d_out;

  size_t off = 0;
  auto alloc = [&](size_t bytes)->size_t{ size_t r = off; off = (off + bytes + 255) & ~(size_t)255; return r; };
  size_t o_xkj  = alloc((size_t)NE*HD*2);
  size_t o_xh   = alloc((size_t)NE*HD*2);
  size_t o_agg  = alloc((size_t)NE*HD*2);
  size_t o_wb2  = alloc((size_t)NBB*HD*HD*2);
  size_t o_wkjT = alloc((size_t)HD*HD*2);
  size_t o_wjiT = alloc((size_t)HD*HD*2);
  size_t o_wlinT= alloc((size_t)HD*HD*2);
  size_t o_wo6  = alloc((size_t)6*HD*HD*2);
  size_t o_g0   = alloc((size_t)NN*HD*2);
  size_t o_g1   = alloc((size_t)NN*HD*2);
  size_t o_s0   = alloc(512);
  size_t o_s1   = alloc(512);
  if (off > ws_size) return;
  char* ws = (char*)d_ws;
  __half* xkj  = (__half*)(ws + o_xkj);
  __half* xh   = (__half*)(ws + o_xh);
  __half* agg  = (__half*)(ws + o_agg);
  __half* wb2  = (__half*)(ws + o_wb2);
  __half* wkjT = (__half*)(ws + o_wkjT);
  __half* wjiT = (__half*)(ws + o_wjiT);
  __half* wlinT= (__half*)(ws + o_wlinT);
  __half* wo6  = (__half*)(ws + o_wo6);
  __half* g0   = (__half*)(ws + o_g0);
  __half* g1   = (__half*)(ws + o_g1);
  float* s0    = (float*)(ws + o_s0);
  float* s1    = (float*)(ws + o_s1);

  hipFuncSetAttribute((const void*)k_edge_pre,     hipFuncAttributeMaxDynamicSharedMemorySize, SH_PRE);
  hipFuncSetAttribute((const void*)k_edge_post,    hipFuncAttributeMaxDynamicSharedMemorySize, SH_POST);
  hipFuncSetAttribute((const void*)k_triplet_mfma, hipFuncAttributeMaxDynamicSharedMemorySize, SH_TRIP);
  hipFuncSetAttribute((const void*)k_mlp_chain,    hipFuncAttributeMaxDynamicSharedMemorySize, SH_MLPC);

  hipMemsetAsync(agg, 0, (size_t)NE*HD*2, stream);
  hipMemsetAsync(g0,  0, (size_t)NN*HD*2, stream);
  hipMemsetAsync(g1,  0, (size_t)NN*HD*2, stream);
  hipMemsetAsync(s0,  0, 512, stream);
  hipMemsetAsync(s1,  0, 512, stream);

  k_prep<<<XBLK+1088,256,0,stream>>>(x, xh, W_bil, wb2, W_kj, W_ji, W_lin,
                                     wkjT, wjiT, wlinT, olW, wo6);

  k_edge_pre<<<(NE+EROWS-1)/EROWS,512,SH_PRE,stream>>>(xh, rbf, nid, wkjT, b_kj, W_rbf,
                                                       olrbf, xkj, g0);
  k_triplet_mfma<<<(NT+TROWS-1)/TROWS,512,SH_TRIP,stream>>>(xkj, sbf, W_sbf, ikj, iji, wb2, agg);
  k_edge_post<<<(NE+EROWS-1)/EROWS,512,SH_POST,stream>>>(xh, rbf, agg, nid, wjiT, b_ji,
                                                         wlinT, b_lin, olrbf + NRR*HD, g1);

  int mlpg = (NN+EROWS-1)/EROWS;
  k_mlp_chain<<<2*mlpg,512,SH_MLPC,stream>>>(g0, g1, wo6, olb, s0, s1);

  k_readout<<<1,128,0,stream>>>(s0, s1, olin, out);
}